// Round 1
// baseline (38043.765 us; speedup 1.0000x reference)
//
#include <hip/hip_runtime.h>

// ---------------- problem constants ----------------
#define NN   4096      // neurons per layer
#define TLEN 200       // stimulus length
#define NT   199       // number of scan steps (T-1)
#define DBUF 16        // spike buffer depth

// ws layout (floats):
//   IN0 [NN*NT], IN3 [NN*NT], v [8*NN], psp [11*NN], bits(u32) [8*NN]

// ---------------- stimulus GEMM: IN = W @ X ----------------
// MODE 0: X(j,tt) = stim[j, tt+1] - 3
// MODE 1: X(j,tt) = (tt+1>=4) ? |stim[j,tt+1]-stim[j,tt]|*10 : 0
template<int MODE>
__global__ void gemm_in(const float* __restrict__ W, const float* __restrict__ stim,
                        float* __restrict__ out) {
  constexpr int BM = 64, BN = 64, BK = 32;
  __shared__ float Ws[BM][BK + 1];
  __shared__ float Xs[BK][BN + 1];
  const int row0 = blockIdx.x * BM;
  const int col0 = blockIdx.y * BN;
  const int tx = threadIdx.x & 15, ty = threadIdx.x >> 4;   // 16x16
  float acc[4][4] = {};
  for (int k0 = 0; k0 < NN; k0 += BK) {
    for (int u = threadIdx.x; u < BM * BK; u += 256) {
      int r = u >> 5, kk = u & 31;                          // BK = 32
      Ws[r][kk] = W[(size_t)(row0 + r) * NN + (k0 + kk)];
    }
    for (int u = threadIdx.x; u < BK * BN; u += 256) {
      int kk = u >> 6, c = u & 63;                          // BN = 64
      int tt = col0 + c;
      float xv = 0.0f;
      if (tt < NT) {
        int j = k0 + kk;
        int tcur = tt + 1;
        if (MODE == 0) {
          xv = stim[(size_t)j * TLEN + tcur] - 3.0f;
        } else {
          xv = (tcur >= 4)
             ? fabsf(stim[(size_t)j * TLEN + tcur] - stim[(size_t)j * TLEN + tcur - 1]) * 10.0f
             : 0.0f;
        }
      }
      Xs[kk][c] = xv;
    }
    __syncthreads();
    #pragma unroll
    for (int kk = 0; kk < BK; ++kk) {
      float wl[4], xl[4];
      #pragma unroll
      for (int b = 0; b < 4; ++b) xl[b] = Xs[kk][tx * 4 + b];
      #pragma unroll
      for (int a = 0; a < 4; ++a) wl[a] = Ws[ty * 4 + a][kk];
      #pragma unroll
      for (int a = 0; a < 4; ++a)
        #pragma unroll
        for (int b = 0; b < 4; ++b) acc[a][b] += wl[a] * xl[b];
    }
    __syncthreads();
  }
  for (int a = 0; a < 4; ++a) {
    int r = row0 + ty * 4 + a;
    for (int b = 0; b < 4; ++b) {
      int c = col0 + tx * 4 + b;
      if (c < NT) out[(size_t)r * NT + c] = acc[a][b];
    }
  }
}

// ---------------- device helpers ----------------
__device__ __forceinline__ void do_lif(int li, int i, float inp, float* v,
                                       unsigned* bits, float* out, int t) {
  int pos = t & 15;
  float vn = v[li * NN + i] * 0.9f + inp;
  unsigned s = (vn >= 1.0f) ? 1u : 0u;
  vn = s ? 0.0f : vn;                        // vn * (1 - s)
  v[li * NN + i] = vn;
  unsigned b = bits[li * NN + i];
  bits[li * NN + i] = (b & ~(1u << pos)) | (s << pos);
  out[((size_t)li * NN + i) * NT + t] = (float)s;
}

// Build a 4096-bit spike mask for synapse k (pre-layer bitmasks + per-pre delays).
__device__ __forceinline__ void build_mask(unsigned* sm, const unsigned* __restrict__ bitsPre,
                                           const int* __restrict__ delK, int pos) {
  for (int w = threadIdx.x; w < NN / 32; w += blockDim.x) {
    unsigned m = 0;
    int j = w * 32;
    #pragma unroll
    for (int b = 0; b < 32; ++b) {
      int slot = (pos - delK[j + b]) & 15;
      m |= ((bitsPre[j + b] >> slot) & 1u) << b;
    }
    sm[w] = m;
  }
}

// One wave computes dot(W_row, spikes) via predicated adds on the LDS mask.
__device__ __forceinline__ float dot_row(const float* __restrict__ Wrow,
                                         const unsigned* sm) {
  int lane = threadIdx.x & 63;
  float acc = 0.0f;
  const float4* W4 = (const float4*)Wrow;
  #pragma unroll 4
  for (int it = lane; it < NN / 4; it += 64) {
    float4 w = W4[it];
    unsigned m = sm[it >> 3];
    int sh = (it & 7) * 4;
    if ((m >> (sh + 0)) & 1u) acc += w.x;
    if ((m >> (sh + 1)) & 1u) acc += w.y;
    if ((m >> (sh + 2)) & 1u) acc += w.z;
    if ((m >> (sh + 3)) & 1u) acc += w.w;
  }
  #pragma unroll
  for (int o = 1; o < 64; o <<= 1) acc += __shfl_xor(acc, o);
  return acc;                                   // all lanes hold the sum
}

// ---------------- per-step phase kernels ----------------
// P1: lif0 (input IN0[:,t]) and lif3 (input IN3[:,t])
__global__ void phase1_k(const float* __restrict__ IN0, const float* __restrict__ IN3,
                         float* v, unsigned* bits, float* out, int t) {
  int i = blockIdx.x * blockDim.x + threadIdx.x;
  do_lif(0, i, IN0[(size_t)i * NT + t], v, bits, out, t);
  do_lif(3, i, IN3[(size_t)i * NT + t], v, bits, out, t);
}

// P2: syn0(pre0)->lif1, syn1(pre0), syn3(pre3)->lif4, syn4(pre3)
__global__ void phase2_k(const float* __restrict__ Wdel, const int* __restrict__ delays,
                         float* v, float* psp, unsigned* bits, float* out, int t) {
  __shared__ unsigned sm[NN / 32];
  const int kArr[4] = {0, 1, 3, 4};
  const int preArr[4] = {0, 0, 3, 3};
  const int liArr[4] = {1, -1, 4, -1};
  int task = blockIdx.y;
  int k = kArr[task], pre = preArr[task], li = liArr[task];
  int pos = t & 15;
  build_mask(sm, bits + pre * NN, delays + k * NN, pos);
  __syncthreads();
  int row = blockIdx.x * 4 + (threadIdx.x >> 6);
  float acc = dot_row(Wdel + (size_t)k * NN * NN + (size_t)row * NN, sm);
  if ((threadIdx.x & 63) == 0) {
    float p = psp[k * NN + row] * 0.8f + acc;
    psp[k * NN + row] = p;
    if (li >= 0) do_lif(li, row, p, v, bits, out, t);
  }
}

// P3: syn2(pre1)->lif2 (inp=2*psp1-p), syn5(pre4)->lif5 (inp=2*psp4-p)
__global__ void phase3_k(const float* __restrict__ Wdel, const int* __restrict__ delays,
                         float* v, float* psp, unsigned* bits, float* out, int t) {
  __shared__ unsigned sm[NN / 32];
  int task = blockIdx.y;
  int k = task ? 5 : 2, pre = task ? 4 : 1, li = task ? 5 : 2, kprev = task ? 4 : 1;
  int pos = t & 15;
  build_mask(sm, bits + pre * NN, delays + k * NN, pos);
  __syncthreads();
  int row = blockIdx.x * 4 + (threadIdx.x >> 6);
  float acc = dot_row(Wdel + (size_t)k * NN * NN + (size_t)row * NN, sm);
  if ((threadIdx.x & 63) == 0) {
    float p = psp[k * NN + row] * 0.8f + acc;
    psp[k * NN + row] = p;
    float inp = 2.0f * psp[kprev * NN + row] - p;
    do_lif(li, row, inp, v, bits, out, t);
  }
}

// P4: task0: syn6(pre2)+syn8(pre5)->lif6 (inp=p6+p8); task1: syn7(pre2); task2: syn9(pre5)
__global__ void phase4_k(const float* __restrict__ Wdel, const int* __restrict__ delays,
                         float* v, float* psp, unsigned* bits, float* out, int t) {
  __shared__ unsigned smA[NN / 32];
  __shared__ unsigned smB[NN / 32];
  int task = blockIdx.y;
  int pos = t & 15;
  int row = blockIdx.x * 4 + (threadIdx.x >> 6);
  if (task == 0) {
    build_mask(smA, bits + 2 * NN, delays + 6 * NN, pos);
    build_mask(smB, bits + 5 * NN, delays + 8 * NN, pos);
    __syncthreads();
    float a6 = dot_row(Wdel + (size_t)6 * NN * NN + (size_t)row * NN, smA);
    float a8 = dot_row(Wdel + (size_t)8 * NN * NN + (size_t)row * NN, smB);
    if ((threadIdx.x & 63) == 0) {
      float p6 = psp[6 * NN + row] * 0.8f + a6; psp[6 * NN + row] = p6;
      float p8 = psp[8 * NN + row] * 0.8f + a8; psp[8 * NN + row] = p8;
      do_lif(6, row, p6 + p8, v, bits, out, t);
    }
  } else {
    int k = (task == 1) ? 7 : 9, pre = (task == 1) ? 2 : 5;
    build_mask(smA, bits + pre * NN, delays + k * NN, pos);
    __syncthreads();
    float a = dot_row(Wdel + (size_t)k * NN * NN + (size_t)row * NN, smA);
    if ((threadIdx.x & 63) == 0) {
      float p = psp[k * NN + row] * 0.8f + a;
      psp[k * NN + row] = p;
    }
  }
}

// P5: syn10(pre6)->lif7 (inp = 2*psp7 + 2*psp9 - p10)
__global__ void phase5_k(const float* __restrict__ Wdel, const int* __restrict__ delays,
                         float* v, float* psp, unsigned* bits, float* out, int t) {
  __shared__ unsigned sm[NN / 32];
  int pos = t & 15;
  build_mask(sm, bits + 6 * NN, delays + 10 * NN, pos);
  __syncthreads();
  int row = blockIdx.x * 4 + (threadIdx.x >> 6);
  float acc = dot_row(Wdel + (size_t)10 * NN * NN + (size_t)row * NN, sm);
  if ((threadIdx.x & 63) == 0) {
    float p = psp[10 * NN + row] * 0.8f + acc;
    psp[10 * NN + row] = p;
    float inp = 2.0f * psp[7 * NN + row] + 2.0f * psp[9 * NN + row] - p;
    do_lif(7, row, inp, v, bits, out, t);
  }
}

// ---------------- launch ----------------
extern "C" void kernel_launch(void* const* d_in, const int* in_sizes, int n_in,
                              void* d_out, int out_size, void* d_ws, size_t ws_size,
                              hipStream_t stream) {
  const float* stim  = (const float*)d_in[0];
  const float* Wsa   = (const float*)d_in[1];
  const float* Wra   = (const float*)d_in[2];
  const float* Wdel  = (const float*)d_in[3];
  const int*   delays= (const int*)d_in[4];
  float* out = (float*)d_out;

  float* IN0 = (float*)d_ws;
  float* IN3 = IN0 + (size_t)NN * NT;
  float* v   = IN3 + (size_t)NN * NT;
  float* psp = v + 8 * NN;
  unsigned* bits = (unsigned*)(psp + 11 * NN);

  size_t need = ((size_t)2 * NN * NT + 27 * NN) * sizeof(float);
  if (ws_size < need) return;   // would corrupt memory otherwise; fail loudly

  // zero state: v(8N) + psp(11N) + bits(8N) are contiguous
  hipMemsetAsync(v, 0, (size_t)(8 + 11 + 8) * NN * sizeof(float), stream);

  // stimulus matvecs hoisted out of the time loop as GEMMs
  dim3 ggrid(NN / 64, (NT + 63) / 64);
  gemm_in<0><<<ggrid, 256, 0, stream>>>(Wsa, stim, IN0);
  gemm_in<1><<<ggrid, 256, 0, stream>>>(Wra, stim, IN3);

  for (int t = 0; t < NT; ++t) {
    phase1_k<<<NN / 256, 256, 0, stream>>>(IN0, IN3, v, bits, out, t);
    phase2_k<<<dim3(NN / 4, 4), 256, 0, stream>>>(Wdel, delays, v, psp, bits, out, t);
    phase3_k<<<dim3(NN / 4, 2), 256, 0, stream>>>(Wdel, delays, v, psp, bits, out, t);
    phase4_k<<<dim3(NN / 4, 3), 256, 0, stream>>>(Wdel, delays, v, psp, bits, out, t);
    phase5_k<<<dim3(NN / 4, 1), 256, 0, stream>>>(Wdel, delays, v, psp, bits, out, t);
  }
}

// Round 2
// 17798.642 us; speedup vs baseline: 2.1375x; 2.1375x over previous
//
#include <hip/hip_runtime.h>

// ---------------- problem constants ----------------
#define NN   4096      // neurons per layer
#define TLEN 200       // stimulus length
#define NT   199       // number of scan steps (T-1)
#define SEG  32        // gather segments per synapse (128 mask words / 4 per seg)

__device__ __forceinline__ void f4add(float4& a, const float4 b) {
  a.x += b.x; a.y += b.y; a.z += b.z; a.w += b.w;
}

// ---------------- stimulus GEMM: IN = W @ X ----------------
// MODE 0: X(j,tt) = stim[j, tt+1] - 3
// MODE 1: X(j,tt) = (tt+1>=4) ? |stim[j,tt+1]-stim[j,tt]|*10 : 0
// TR   1: out[tt*NN + r]  (time-major, for sparse path)   0: out[r*NT + tt]
template<int MODE, int TR>
__global__ void gemm_in(const float* __restrict__ W, const float* __restrict__ stim,
                        float* __restrict__ out) {
  constexpr int BM = 64, BN = 64, BK = 32;
  __shared__ float Ws[BM][BK + 1];
  __shared__ float Xs[BK][BN + 1];
  const int row0 = blockIdx.x * BM;
  const int col0 = blockIdx.y * BN;
  const int tx = threadIdx.x & 15, ty = threadIdx.x >> 4;   // 16x16
  float acc[4][4] = {};
  for (int k0 = 0; k0 < NN; k0 += BK) {
    for (int u = threadIdx.x; u < BM * BK; u += 256) {
      int r = u >> 5, kk = u & 31;
      Ws[r][kk] = W[(size_t)(row0 + r) * NN + (k0 + kk)];
    }
    for (int u = threadIdx.x; u < BK * BN; u += 256) {
      int kk = u >> 6, c = u & 63;
      int tt = col0 + c;
      float xv = 0.0f;
      if (tt < NT) {
        int j = k0 + kk;
        int tcur = tt + 1;
        if (MODE == 0) {
          xv = stim[(size_t)j * TLEN + tcur] - 3.0f;
        } else {
          xv = (tcur >= 4)
             ? fabsf(stim[(size_t)j * TLEN + tcur] - stim[(size_t)j * TLEN + tcur - 1]) * 10.0f
             : 0.0f;
        }
      }
      Xs[kk][c] = xv;
    }
    __syncthreads();
    #pragma unroll
    for (int kk = 0; kk < BK; ++kk) {
      float wl[4], xl[4];
      #pragma unroll
      for (int b = 0; b < 4; ++b) xl[b] = Xs[kk][tx * 4 + b];
      #pragma unroll
      for (int a = 0; a < 4; ++a) wl[a] = Ws[ty * 4 + a][kk];
      #pragma unroll
      for (int a = 0; a < 4; ++a)
        #pragma unroll
        for (int b = 0; b < 4; ++b) acc[a][b] += wl[a] * xl[b];
    }
    __syncthreads();
  }
  for (int a = 0; a < 4; ++a) {
    int r = row0 + ty * 4 + a;
    for (int b = 0; b < 4; ++b) {
      int c = col0 + tx * 4 + b;
      if (c < NT) {
        if (TR) out[(size_t)c * NN + r] = acc[a][b];
        else    out[(size_t)r * NT + c] = acc[a][b];
      }
    }
  }
}

// ======================= SPARSE (transposed-gather) PATH =======================

// W_del[k] transpose: WT[k][j][i] = W[k][i][j]
__global__ void transpose_k(const float* __restrict__ W, float* __restrict__ WT) {
  __shared__ float tile[32][33];
  const int k = blockIdx.z;
  const int i0 = blockIdx.x * 32, j0 = blockIdx.y * 32;
  const float* Wk = W + (size_t)k * NN * NN;
  float* WTk = WT + (size_t)k * NN * NN;
  int tx = threadIdx.x & 31, ty = threadIdx.x >> 5;   // 32x8
  #pragma unroll
  for (int m = 0; m < 4; ++m) {
    int ii = ty + m * 8;
    tile[ii][tx] = Wk[(size_t)(i0 + ii) * NN + (j0 + tx)];
  }
  __syncthreads();
  #pragma unroll
  for (int m = 0; m < 4; ++m) {
    int jj = ty + m * 8;
    WTk[(size_t)(j0 + jj) * NN + (i0 + tx)] = tile[tx][jj];
  }
}

// LIF update; returns the updated 16-slot spike-history word
__device__ __forceinline__ unsigned lif_upd(int li, int i, float inp, float* v,
                                            unsigned* bits, float* stage, int t) {
  int pos = t & 15;
  size_t idx = (size_t)li * NN + i;
  float vn = v[idx] * 0.9f + inp;
  unsigned s = (vn >= 1.0f) ? 1u : 0u;
  v[idx] = s ? 0.0f : vn;
  unsigned b = bits[idx];
  b = (b & ~(1u << pos)) | (s << pos);
  bits[idx] = b;
  stage[((size_t)t * 8 + li) * NN + i] = (float)s;
  return b;
}

// Build one 32-bit delayed-spike mask word for synapse k from LDS history words
__device__ __forceinline__ void mask_words(const unsigned* nb, int k,
                                           const int* __restrict__ delays,
                                           unsigned* masks, int blk, int w, int pos) {
  int j0 = blk * 256 + w * 32;
  unsigned m = 0;
  #pragma unroll
  for (int b = 0; b < 32; ++b) {
    int slot = (pos - delays[(size_t)k * NN + j0 + b]) & 15;
    m |= ((nb[w * 32 + b] >> slot) & 1u) << b;
  }
  masks[k * 128 + blk * 8 + w] = m;
}

// P1: lif0, lif3 + masks for synapses 0,1 (pre 0) and 3,4 (pre 3)
__global__ void sp_phase1(const float* __restrict__ IN0, const float* __restrict__ IN3,
                          const int* __restrict__ delays, float* v, unsigned* bits,
                          unsigned* masks, float* stage, int t) {
  __shared__ unsigned nb0[256], nb3[256];
  int i = blockIdx.x * 256 + threadIdx.x;
  nb0[threadIdx.x] = lif_upd(0, i, IN0[(size_t)t * NN + i], v, bits, stage, t);
  nb3[threadIdx.x] = lif_upd(3, i, IN3[(size_t)t * NN + i], v, bits, stage, t);
  __syncthreads();
  if (threadIdx.x < 32) {
    int which = threadIdx.x >> 3, w = threadIdx.x & 7;
    const int kk[4] = {0, 1, 3, 4};
    mask_words(which < 2 ? nb0 : nb3, kk[which], delays, masks, blockIdx.x, w, t & 15);
  }
}

// Gather: partial[k][seg][:] = sum over spiking columns j in segment of WT[k][j][:]
// Deterministic: ascending-bit decode + fixed 4-accumulator stripe reduction.
template<int K0, int K1, int K2, int K3>
__global__ __launch_bounds__(256) void sp_gather(const float* __restrict__ WT,
                                                 const unsigned* __restrict__ masks,
                                                 float* __restrict__ partial) {
  const int ks[4] = {K0, K1, K2, K3};
  const int k = ks[blockIdx.y];
  const int seg = blockIdx.x & (SEG - 1);
  const int chunk = blockIdx.x >> 5;            // 0..3 -> 1024-float output chunk
  __shared__ int list[128];
  __shared__ int cnt_s;
  if (threadIdx.x == 0) {
    int c = 0;
    #pragma unroll
    for (int w = 0; w < 4; ++w) {
      unsigned m = masks[k * 128 + seg * 4 + w];
      int jb = seg * 128 + w * 32;
      while (m) { int b = __ffs(m) - 1; m &= m - 1; list[c++] = jb + b; }
    }
    cnt_s = c;
  }
  __syncthreads();
  const int cnt = cnt_s;
  const float* base = WT + (size_t)k * NN * NN + chunk * 1024 + threadIdx.x * 4;
  float4 a0 = {0, 0, 0, 0}, a1 = a0, a2 = a0, a3 = a0;
  int n = 0;
  for (; n + 3 < cnt; n += 4) {
    f4add(a0, *(const float4*)(base + (size_t)list[n]     * NN));
    f4add(a1, *(const float4*)(base + (size_t)list[n + 1] * NN));
    f4add(a2, *(const float4*)(base + (size_t)list[n + 2] * NN));
    f4add(a3, *(const float4*)(base + (size_t)list[n + 3] * NN));
  }
  for (; n < cnt; ++n) f4add(a0, *(const float4*)(base + (size_t)list[n] * NN));
  f4add(a0, a1); f4add(a2, a3); f4add(a0, a2);
  *(float4*)(partial + ((size_t)k * SEG + seg) * NN + chunk * 1024 + threadIdx.x * 4) = a0;
}

__device__ __forceinline__ float sumseg(const float* __restrict__ partial, int k, int i) {
  float s = 0.0f;
  #pragma unroll
  for (int g = 0; g < SEG; ++g) s += partial[((size_t)k * SEG + g) * NN + i];
  return s;
}

// R2: psp0->lif1, psp1, psp3->lif4, psp4; masks for syn2(pre1), syn5(pre4)
__global__ void sp_r2(const float* __restrict__ partial, const int* __restrict__ delays,
                      float* v, float* psp, unsigned* bits, unsigned* masks,
                      float* stage, int t) {
  __shared__ unsigned nb1[256], nb4[256];
  int i = blockIdx.x * 256 + threadIdx.x;
  float p0 = psp[0 * NN + i] * 0.8f + sumseg(partial, 0, i); psp[0 * NN + i] = p0;
  nb1[threadIdx.x] = lif_upd(1, i, p0, v, bits, stage, t);
  float p1 = psp[1 * NN + i] * 0.8f + sumseg(partial, 1, i); psp[1 * NN + i] = p1;
  float p3 = psp[3 * NN + i] * 0.8f + sumseg(partial, 3, i); psp[3 * NN + i] = p3;
  nb4[threadIdx.x] = lif_upd(4, i, p3, v, bits, stage, t);
  float p4 = psp[4 * NN + i] * 0.8f + sumseg(partial, 4, i); psp[4 * NN + i] = p4;
  __syncthreads();
  if (threadIdx.x < 16) {
    int which = threadIdx.x >> 3, w = threadIdx.x & 7;
    mask_words(which ? nb4 : nb1, which ? 5 : 2, delays, masks, blockIdx.x, w, t & 15);
  }
}

// R3: psp2->lif2(2*psp1-p2), psp5->lif5(2*psp4-p5); masks for syn6,7(pre2), syn8,9(pre5)
__global__ void sp_r3(const float* __restrict__ partial, const int* __restrict__ delays,
                      float* v, float* psp, unsigned* bits, unsigned* masks,
                      float* stage, int t) {
  __shared__ unsigned nb2[256], nb5[256];
  int i = blockIdx.x * 256 + threadIdx.x;
  float p2 = psp[2 * NN + i] * 0.8f + sumseg(partial, 2, i); psp[2 * NN + i] = p2;
  nb2[threadIdx.x] = lif_upd(2, i, 2.0f * psp[1 * NN + i] - p2, v, bits, stage, t);
  float p5 = psp[5 * NN + i] * 0.8f + sumseg(partial, 5, i); psp[5 * NN + i] = p5;
  nb5[threadIdx.x] = lif_upd(5, i, 2.0f * psp[4 * NN + i] - p5, v, bits, stage, t);
  __syncthreads();
  if (threadIdx.x < 32) {
    int which = threadIdx.x >> 3, w = threadIdx.x & 7;
    const int kk[4] = {6, 7, 8, 9};
    mask_words(which < 2 ? nb2 : nb5, kk[which], delays, masks, blockIdx.x, w, t & 15);
  }
}

// R4: psp6,psp8 -> lif6(p6+p8); psp7, psp9 stored; masks for syn10(pre6)
__global__ void sp_r4(const float* __restrict__ partial, const int* __restrict__ delays,
                      float* v, float* psp, unsigned* bits, unsigned* masks,
                      float* stage, int t) {
  __shared__ unsigned nb6[256];
  int i = blockIdx.x * 256 + threadIdx.x;
  float p6 = psp[6 * NN + i] * 0.8f + sumseg(partial, 6, i); psp[6 * NN + i] = p6;
  float p8 = psp[8 * NN + i] * 0.8f + sumseg(partial, 8, i); psp[8 * NN + i] = p8;
  nb6[threadIdx.x] = lif_upd(6, i, p6 + p8, v, bits, stage, t);
  float p7 = psp[7 * NN + i] * 0.8f + sumseg(partial, 7, i); psp[7 * NN + i] = p7;
  float p9 = psp[9 * NN + i] * 0.8f + sumseg(partial, 9, i); psp[9 * NN + i] = p9;
  __syncthreads();
  if (threadIdx.x < 8) {
    mask_words(nb6, 10, delays, masks, blockIdx.x, threadIdx.x, t & 15);
  }
}

// R5: psp10 -> lif7(2*psp7+2*psp9-p10); fused next-step P1 (lif0,lif3 + masks 0,1,3,4)
__global__ void sp_r5(const float* __restrict__ partial, const int* __restrict__ delays,
                      float* v, float* psp, unsigned* bits, unsigned* masks,
                      float* stage, const float* __restrict__ IN0,
                      const float* __restrict__ IN3, int t) {
  __shared__ unsigned nb0[256], nb3[256];
  int i = blockIdx.x * 256 + threadIdx.x;
  float p10 = psp[10 * NN + i] * 0.8f + sumseg(partial, 10, i); psp[10 * NN + i] = p10;
  float inp = 2.0f * psp[7 * NN + i] + 2.0f * psp[9 * NN + i] - p10;
  lif_upd(7, i, inp, v, bits, stage, t);
  int tp = t + 1;
  if (tp < NT) {
    nb0[threadIdx.x] = lif_upd(0, i, IN0[(size_t)tp * NN + i], v, bits, stage, tp);
    nb3[threadIdx.x] = lif_upd(3, i, IN3[(size_t)tp * NN + i], v, bits, stage, tp);
    __syncthreads();
    if (threadIdx.x < 32) {
      int which = threadIdx.x >> 3, w = threadIdx.x & 7;
      const int kk[4] = {0, 1, 3, 4};
      mask_words(which < 2 ? nb0 : nb3, kk[which], delays, masks, blockIdx.x, w, tp & 15);
    }
  }
}

// Final spike transpose: out[li][i][t] = stage[t][li][i]
__global__ void out_tr(const float* __restrict__ stage, float* __restrict__ out) {
  __shared__ float tile[32][33];
  const int li = blockIdx.z;
  const int i0 = blockIdx.x * 32, t0 = blockIdx.y * 32;
  int tx = threadIdx.x & 31, ty = threadIdx.x >> 5;
  #pragma unroll
  for (int m = 0; m < 4; ++m) {
    int tt = t0 + ty + m * 8;
    tile[ty + m * 8][tx] = (tt < NT) ? stage[((size_t)tt * 8 + li) * NN + i0 + tx] : 0.0f;
  }
  __syncthreads();
  #pragma unroll
  for (int m = 0; m < 4; ++m) {
    int ii = i0 + ty + m * 8;
    int tt = t0 + tx;
    if (tt < NT) out[((size_t)li * NN + ii) * NT + tt] = tile[tx][ty + m * 8];
  }
}

// ======================= DENSE FALLBACK (round-1) =======================

__device__ __forceinline__ void do_lif(int li, int i, float inp, float* v,
                                       unsigned* bits, float* out, int t) {
  int pos = t & 15;
  float vn = v[li * NN + i] * 0.9f + inp;
  unsigned s = (vn >= 1.0f) ? 1u : 0u;
  vn = s ? 0.0f : vn;
  v[li * NN + i] = vn;
  unsigned b = bits[li * NN + i];
  bits[li * NN + i] = (b & ~(1u << pos)) | (s << pos);
  out[((size_t)li * NN + i) * NT + t] = (float)s;
}

__device__ __forceinline__ void build_mask(unsigned* sm, const unsigned* __restrict__ bitsPre,
                                           const int* __restrict__ delK, int pos) {
  for (int w = threadIdx.x; w < NN / 32; w += blockDim.x) {
    unsigned m = 0;
    int j = w * 32;
    #pragma unroll
    for (int b = 0; b < 32; ++b) {
      int slot = (pos - delK[j + b]) & 15;
      m |= ((bitsPre[j + b] >> slot) & 1u) << b;
    }
    sm[w] = m;
  }
}

__device__ __forceinline__ float dot_row(const float* __restrict__ Wrow,
                                         const unsigned* sm) {
  int lane = threadIdx.x & 63;
  float acc = 0.0f;
  const float4* W4 = (const float4*)Wrow;
  #pragma unroll 4
  for (int it = lane; it < NN / 4; it += 64) {
    float4 w = W4[it];
    unsigned m = sm[it >> 3];
    int sh = (it & 7) * 4;
    if ((m >> (sh + 0)) & 1u) acc += w.x;
    if ((m >> (sh + 1)) & 1u) acc += w.y;
    if ((m >> (sh + 2)) & 1u) acc += w.z;
    if ((m >> (sh + 3)) & 1u) acc += w.w;
  }
  #pragma unroll
  for (int o = 1; o < 64; o <<= 1) acc += __shfl_xor(acc, o);
  return acc;
}

__global__ void phase1_k(const float* __restrict__ IN0, const float* __restrict__ IN3,
                         float* v, unsigned* bits, float* out, int t) {
  int i = blockIdx.x * blockDim.x + threadIdx.x;
  do_lif(0, i, IN0[(size_t)i * NT + t], v, bits, out, t);
  do_lif(3, i, IN3[(size_t)i * NT + t], v, bits, out, t);
}

__global__ void phase2_k(const float* __restrict__ Wdel, const int* __restrict__ delays,
                         float* v, float* psp, unsigned* bits, float* out, int t) {
  __shared__ unsigned sm[NN / 32];
  const int kArr[4] = {0, 1, 3, 4};
  const int preArr[4] = {0, 0, 3, 3};
  const int liArr[4] = {1, -1, 4, -1};
  int task = blockIdx.y;
  int k = kArr[task], pre = preArr[task], li = liArr[task];
  int pos = t & 15;
  build_mask(sm, bits + pre * NN, delays + k * NN, pos);
  __syncthreads();
  int row = blockIdx.x * 4 + (threadIdx.x >> 6);
  float acc = dot_row(Wdel + (size_t)k * NN * NN + (size_t)row * NN, sm);
  if ((threadIdx.x & 63) == 0) {
    float p = psp[k * NN + row] * 0.8f + acc;
    psp[k * NN + row] = p;
    if (li >= 0) do_lif(li, row, p, v, bits, out, t);
  }
}

__global__ void phase3_k(const float* __restrict__ Wdel, const int* __restrict__ delays,
                         float* v, float* psp, unsigned* bits, float* out, int t) {
  __shared__ unsigned sm[NN / 32];
  int task = blockIdx.y;
  int k = task ? 5 : 2, pre = task ? 4 : 1, li = task ? 5 : 2, kprev = task ? 4 : 1;
  int pos = t & 15;
  build_mask(sm, bits + pre * NN, delays + k * NN, pos);
  __syncthreads();
  int row = blockIdx.x * 4 + (threadIdx.x >> 6);
  float acc = dot_row(Wdel + (size_t)k * NN * NN + (size_t)row * NN, sm);
  if ((threadIdx.x & 63) == 0) {
    float p = psp[k * NN + row] * 0.8f + acc;
    psp[k * NN + row] = p;
    float inp = 2.0f * psp[kprev * NN + row] - p;
    do_lif(li, row, inp, v, bits, out, t);
  }
}

__global__ void phase4_k(const float* __restrict__ Wdel, const int* __restrict__ delays,
                         float* v, float* psp, unsigned* bits, float* out, int t) {
  __shared__ unsigned smA[NN / 32];
  __shared__ unsigned smB[NN / 32];
  int task = blockIdx.y;
  int pos = t & 15;
  int row = blockIdx.x * 4 + (threadIdx.x >> 6);
  if (task == 0) {
    build_mask(smA, bits + 2 * NN, delays + 6 * NN, pos);
    build_mask(smB, bits + 5 * NN, delays + 8 * NN, pos);
    __syncthreads();
    float a6 = dot_row(Wdel + (size_t)6 * NN * NN + (size_t)row * NN, smA);
    float a8 = dot_row(Wdel + (size_t)8 * NN * NN + (size_t)row * NN, smB);
    if ((threadIdx.x & 63) == 0) {
      float p6 = psp[6 * NN + row] * 0.8f + a6; psp[6 * NN + row] = p6;
      float p8 = psp[8 * NN + row] * 0.8f + a8; psp[8 * NN + row] = p8;
      do_lif(6, row, p6 + p8, v, bits, out, t);
    }
  } else {
    int k = (task == 1) ? 7 : 9, pre = (task == 1) ? 2 : 5;
    build_mask(smA, bits + pre * NN, delays + k * NN, pos);
    __syncthreads();
    float a = dot_row(Wdel + (size_t)k * NN * NN + (size_t)row * NN, smA);
    if ((threadIdx.x & 63) == 0) {
      float p = psp[k * NN + row] * 0.8f + a;
      psp[k * NN + row] = p;
    }
  }
}

__global__ void phase5_k(const float* __restrict__ Wdel, const int* __restrict__ delays,
                         float* v, float* psp, unsigned* bits, float* out, int t) {
  __shared__ unsigned sm[NN / 32];
  int pos = t & 15;
  build_mask(sm, bits + 6 * NN, delays + 10 * NN, pos);
  __syncthreads();
  int row = blockIdx.x * 4 + (threadIdx.x >> 6);
  float acc = dot_row(Wdel + (size_t)10 * NN * NN + (size_t)row * NN, sm);
  if ((threadIdx.x & 63) == 0) {
    float p = psp[10 * NN + row] * 0.8f + acc;
    psp[10 * NN + row] = p;
    float inp = 2.0f * psp[7 * NN + row] + 2.0f * psp[9 * NN + row] - p;
    do_lif(7, row, inp, v, bits, out, t);
  }
}

// ---------------- launch ----------------
extern "C" void kernel_launch(void* const* d_in, const int* in_sizes, int n_in,
                              void* d_out, int out_size, void* d_ws, size_t ws_size,
                              hipStream_t stream) {
  const float* stim   = (const float*)d_in[0];
  const float* Wsa    = (const float*)d_in[1];
  const float* Wra    = (const float*)d_in[2];
  const float* Wdel   = (const float*)d_in[3];
  const int*   delays = (const int*)d_in[4];
  float* out = (float*)d_out;
  float* ws  = (float*)d_ws;

  // ---- sparse layout ----
  float* WT   = ws;
  float* sIN0 = WT + (size_t)11 * NN * NN;
  float* sIN3 = sIN0 + (size_t)NN * NT;
  float* sv   = sIN3 + (size_t)NN * NT;
  float* spsp = sv + 8 * NN;
  unsigned* sbits  = (unsigned*)(spsp + 11 * NN);
  unsigned* smasks = sbits + 8 * NN;
  float* spart  = (float*)(smasks + 11 * 128);
  float* sstage = spart + (size_t)11 * SEG * NN;
  float* send   = sstage + (size_t)NT * 8 * NN;
  size_t need_sparse = (size_t)(send - ws) * sizeof(float);

  if (ws_size >= need_sparse) {
    // zero state: v(8N) + psp(11N) + bits(8N) contiguous
    hipMemsetAsync(sv, 0, (size_t)(8 + 11 + 8) * NN * sizeof(float), stream);
    transpose_k<<<dim3(NN / 32, NN / 32, 11), 256, 0, stream>>>(Wdel, WT);
    dim3 gg(NN / 64, (NT + 63) / 64);
    gemm_in<0, 1><<<gg, 256, 0, stream>>>(Wsa, stim, sIN0);
    gemm_in<1, 1><<<gg, 256, 0, stream>>>(Wra, stim, sIN3);
    sp_phase1<<<16, 256, 0, stream>>>(sIN0, sIN3, delays, sv, sbits, smasks, sstage, 0);
    for (int t = 0; t < NT; ++t) {
      sp_gather<0, 1, 3, 4><<<dim3(4 * SEG, 4), 256, 0, stream>>>(WT, smasks, spart);
      sp_r2<<<16, 256, 0, stream>>>(spart, delays, sv, spsp, sbits, smasks, sstage, t);
      sp_gather<2, 5, 0, 0><<<dim3(4 * SEG, 2), 256, 0, stream>>>(WT, smasks, spart);
      sp_r3<<<16, 256, 0, stream>>>(spart, delays, sv, spsp, sbits, smasks, sstage, t);
      sp_gather<6, 7, 8, 9><<<dim3(4 * SEG, 4), 256, 0, stream>>>(WT, smasks, spart);
      sp_r4<<<16, 256, 0, stream>>>(spart, delays, sv, spsp, sbits, smasks, sstage, t);
      sp_gather<10, 0, 0, 0><<<dim3(4 * SEG, 1), 256, 0, stream>>>(WT, smasks, spart);
      sp_r5<<<16, 256, 0, stream>>>(spart, delays, sv, spsp, sbits, smasks, sstage,
                                    sIN0, sIN3, t);
    }
    out_tr<<<dim3(NN / 32, (NT + 31) / 32, 8), 256, 0, stream>>>(sstage, out);
    return;
  }

  // ---- dense fallback (round-1 layout) ----
  float* IN0 = ws;
  float* IN3 = IN0 + (size_t)NN * NT;
  float* v   = IN3 + (size_t)NN * NT;
  float* psp = v + 8 * NN;
  unsigned* bits = (unsigned*)(psp + 11 * NN);
  size_t need_dense = ((size_t)2 * NN * NT + 27 * NN) * sizeof(float);
  if (ws_size < need_dense) return;

  hipMemsetAsync(v, 0, (size_t)(8 + 11 + 8) * NN * sizeof(float), stream);
  dim3 ggrid(NN / 64, (NT + 63) / 64);
  gemm_in<0, 0><<<ggrid, 256, 0, stream>>>(Wsa, stim, IN0);
  gemm_in<1, 0><<<ggrid, 256, 0, stream>>>(Wra, stim, IN3);
  for (int t = 0; t < NT; ++t) {
    phase1_k<<<NN / 256, 256, 0, stream>>>(IN0, IN3, v, bits, out, t);
    phase2_k<<<dim3(NN / 4, 4), 256, 0, stream>>>(Wdel, delays, v, psp, bits, out, t);
    phase3_k<<<dim3(NN / 4, 2), 256, 0, stream>>>(Wdel, delays, v, psp, bits, out, t);
    phase4_k<<<dim3(NN / 4, 3), 256, 0, stream>>>(Wdel, delays, v, psp, bits, out, t);
    phase5_k<<<dim3(NN / 4, 1), 256, 0, stream>>>(Wdel, delays, v, psp, bits, out, t);
  }
}

// Round 4
// 14800.714 us; speedup vs baseline: 2.5704x; 1.2026x over previous
//
#include <hip/hip_runtime.h>

// ---------------- problem constants ----------------
#define NN   4096      // neurons per layer
#define TLEN 200       // stimulus length
#define NT   199       // number of scan steps (T-1)
#define SEG  32        // gather segments per synapse (128 pre-neurons each)

__device__ __forceinline__ void f4add(float4& a, const float4 b) {
  a.x += b.x; a.y += b.y; a.z += b.z; a.w += b.w;
}

// ---------------- stimulus GEMM: IN[t][r] = (W @ X)[r][t]  (time-major) ----------------
// MODE 0: X(j,tt) = stim[j, tt+1] - 3
// MODE 1: X(j,tt) = (tt+1>=4) ? |stim[j,tt+1]-stim[j,tt]|*10 : 0
template<int MODE>
__global__ void gemm_in(const float* __restrict__ W, const float* __restrict__ stim,
                        float* __restrict__ out) {
  constexpr int BM = 64, BN = 64, BK = 32;
  __shared__ float Ws[BM][BK + 1];
  __shared__ float Xs[BK][BN + 1];
  const int row0 = blockIdx.x * BM;
  const int col0 = blockIdx.y * BN;
  const int tx = threadIdx.x & 15, ty = threadIdx.x >> 4;   // 16x16
  float acc[4][4] = {};
  for (int k0 = 0; k0 < NN; k0 += BK) {
    for (int u = threadIdx.x; u < BM * BK; u += 256) {
      int r = u >> 5, kk = u & 31;
      Ws[r][kk] = W[(size_t)(row0 + r) * NN + (k0 + kk)];
    }
    for (int u = threadIdx.x; u < BK * BN; u += 256) {
      int kk = u >> 6, c = u & 63;
      int tt = col0 + c;
      float xv = 0.0f;
      if (tt < NT) {
        int j = k0 + kk;
        int tcur = tt + 1;
        if (MODE == 0) {
          xv = stim[(size_t)j * TLEN + tcur] - 3.0f;
        } else {
          xv = (tcur >= 4)
             ? fabsf(stim[(size_t)j * TLEN + tcur] - stim[(size_t)j * TLEN + tcur - 1]) * 10.0f
             : 0.0f;
        }
      }
      Xs[kk][c] = xv;
    }
    __syncthreads();
    #pragma unroll
    for (int kk = 0; kk < BK; ++kk) {
      float wl[4], xl[4];
      #pragma unroll
      for (int b = 0; b < 4; ++b) xl[b] = Xs[kk][tx * 4 + b];
      #pragma unroll
      for (int a = 0; a < 4; ++a) wl[a] = Ws[ty * 4 + a][kk];
      #pragma unroll
      for (int a = 0; a < 4; ++a)
        #pragma unroll
        for (int b = 0; b < 4; ++b) acc[a][b] += wl[a] * xl[b];
    }
    __syncthreads();
  }
  for (int a = 0; a < 4; ++a) {
    int r = row0 + ty * 4 + a;
    for (int b = 0; b < 4; ++b) {
      int c = col0 + tx * 4 + b;
      if (c < NT) out[(size_t)c * NN + r] = acc[a][b];
    }
  }
}

// W_del[k] transpose: WT[k][j][i] = W[k][i][j]
__global__ void transpose_k(const float* __restrict__ W, float* __restrict__ WT) {
  __shared__ float tile[32][33];
  const int k = blockIdx.z;
  const int i0 = blockIdx.x * 32, j0 = blockIdx.y * 32;
  const float* Wk = W + (size_t)k * NN * NN;
  float* WTk = WT + (size_t)k * NN * NN;
  int tx = threadIdx.x & 31, ty = threadIdx.x >> 5;   // 32x8
  #pragma unroll
  for (int m = 0; m < 4; ++m) {
    int ii = ty + m * 8;
    tile[ii][tx] = Wk[(size_t)(i0 + ii) * NN + (j0 + tx)];
  }
  __syncthreads();
  #pragma unroll
  for (int m = 0; m < 4; ++m) {
    int jj = ty + m * 8;
    WTk[(size_t)(j0 + jj) * NN + (i0 + tx)] = tile[tx][jj];
  }
}

// LIF update; returns the updated 16-slot spike-history word
__device__ __forceinline__ unsigned lif_upd(int li, int i, float inp, float* v,
                                            unsigned* bits, float* stage, int t) {
  int pos = t & 15;
  size_t idx = (size_t)li * NN + i;
  float vn = v[idx] * 0.9f + inp;
  unsigned s = (vn >= 1.0f) ? 1u : 0u;
  v[idx] = s ? 0.0f : vn;
  unsigned b = bits[idx];
  b = (b & ~(1u << pos)) | (s << pos);
  bits[idx] = b;
  stage[((size_t)t * 8 + li) * NN + i] = (float)s;
  return b;
}

// Build one 32-bit delayed-spike mask word for synapse k from LDS history words
__device__ __forceinline__ void mask_words(const unsigned* nb, int k,
                                           const int* __restrict__ delays,
                                           unsigned* masks, int blk, int w, int pos) {
  int j0 = blk * 256 + w * 32;
  unsigned m = 0;
  #pragma unroll
  for (int b = 0; b < 32; ++b) {
    int slot = (pos - delays[(size_t)k * NN + j0 + b]) & 15;
    m |= ((nb[w * 32 + b] >> slot) & 1u) << b;
  }
  masks[k * 128 + blk * 8 + w] = m;
}

// Gather for up to 6 synapses (blockIdx.y picks one):
// partial[k][seg][chunk] = sum over spiking pre j in segment of WT[k][j][chunk]
// Deterministic: ascending-j decode + fixed 4-accumulator stripe reduction.
__global__ __launch_bounds__(256) void sp_gather6(
    const float* __restrict__ WT, const unsigned* __restrict__ masks,
    float* __restrict__ partial, int k0, int k1, int k2, int k3, int k4, int k5) {
  const int kk[6] = {k0, k1, k2, k3, k4, k5};
  const int k = kk[blockIdx.y];
  const int seg = blockIdx.x & (SEG - 1);
  const int chunk = blockIdx.x >> 5;            // 0..3 -> 1024-float output chunk
  __shared__ int list[128];
  __shared__ int cnts[4];
  const int tid = threadIdx.x;
  if (tid < 4) cnts[tid] = __popc(masks[k * 128 + seg * 4 + tid]);
  __syncthreads();
  const int o1 = cnts[0], o2 = o1 + cnts[1], o3 = o2 + cnts[2];
  const int cnt = o3 + cnts[3];
  if (tid < 4) {
    int off = (tid == 0) ? 0 : (tid == 1) ? o1 : (tid == 2) ? o2 : o3;
    unsigned m = masks[k * 128 + seg * 4 + tid];
    int jb = seg * 128 + tid * 32;
    while (m) { int b = __ffs(m) - 1; m &= m - 1; list[off++] = jb + b; }
  }
  __syncthreads();
  const float* base = WT + (size_t)k * NN * NN + chunk * 1024 + tid * 4;
  float4 a0 = {0, 0, 0, 0}, a1 = a0, a2 = a0, a3 = a0;
  int n = 0;
  for (; n + 3 < cnt; n += 4) {
    f4add(a0, *(const float4*)(base + (size_t)list[n]     * NN));
    f4add(a1, *(const float4*)(base + (size_t)list[n + 1] * NN));
    f4add(a2, *(const float4*)(base + (size_t)list[n + 2] * NN));
    f4add(a3, *(const float4*)(base + (size_t)list[n + 3] * NN));
  }
  for (; n < cnt; ++n) f4add(a0, *(const float4*)(base + (size_t)list[n] * NN));
  f4add(a0, a1); f4add(a2, a3); f4add(a0, a2);
  *(float4*)(partial + ((size_t)k * SEG + seg) * NN + chunk * 1024 + tid * 4) = a0;
}

__device__ __forceinline__ float sumseg(const float* __restrict__ partial, int k, int i) {
  float s = 0.0f;
  #pragma unroll
  for (int g = 0; g < SEG; ++g) s += partial[((size_t)k * SEG + g) * NN + i];
  return s;
}

// Fused elementwise stages. tX = step index for stage X, or -1 (disabled).
// E1: lif0,lif3 + masks 0,1,3,4     E2: psp0->lif1, psp1, psp3->lif4, psp4 + masks 2,5
// E3: psp2->lif2, psp5->lif5 + masks 6,7,8,9    E4: psp6,8->lif6, psp7,9 + mask 10
// E5: psp10->lif7
// stash layout: [0,1]=2*psp1 (parity), [2,3]=2*psp4, [4,5]=2*psp7+2*psp9
__global__ void e_combo(const float* __restrict__ partial, const int* __restrict__ delays,
                        float* v, float* psp, unsigned* bits, unsigned* masks,
                        float* stage, const float* __restrict__ IN0,
                        const float* __restrict__ IN3, float* stash,
                        int t1, int t2, int t3, int t4, int t5) {
  if (t1 >= NT) t1 = -1;
  if (t2 >= NT) t2 = -1;
  if (t3 >= NT) t3 = -1;
  if (t4 >= NT) t4 = -1;
  if (t5 >= NT) t5 = -1;
  __shared__ unsigned nb0[256], nb1[256], nb2[256], nb3[256], nb4[256], nb5[256], nb6[256];
  const int i = blockIdx.x * 256 + threadIdx.x;
  if (t3 >= 0) {
    float p2 = psp[2 * NN + i] * 0.8f + sumseg(partial, 2, i); psp[2 * NN + i] = p2;
    nb2[threadIdx.x] = lif_upd(2, i, stash[(size_t)(t3 & 1) * NN + i] - p2, v, bits, stage, t3);
    float p5 = psp[5 * NN + i] * 0.8f + sumseg(partial, 5, i); psp[5 * NN + i] = p5;
    nb5[threadIdx.x] = lif_upd(5, i, stash[(size_t)(2 + (t3 & 1)) * NN + i] - p5, v, bits, stage, t3);
  }
  if (t4 >= 0) {
    float p6 = psp[6 * NN + i] * 0.8f + sumseg(partial, 6, i); psp[6 * NN + i] = p6;
    float p8 = psp[8 * NN + i] * 0.8f + sumseg(partial, 8, i); psp[8 * NN + i] = p8;
    nb6[threadIdx.x] = lif_upd(6, i, p6 + p8, v, bits, stage, t4);
    float p7 = psp[7 * NN + i] * 0.8f + sumseg(partial, 7, i); psp[7 * NN + i] = p7;
    float p9 = psp[9 * NN + i] * 0.8f + sumseg(partial, 9, i); psp[9 * NN + i] = p9;
    stash[(size_t)(4 + (t4 & 1)) * NN + i] = 2.0f * p7 + 2.0f * p9;
  }
  if (t5 >= 0) {
    float p10 = psp[10 * NN + i] * 0.8f + sumseg(partial, 10, i); psp[10 * NN + i] = p10;
    lif_upd(7, i, stash[(size_t)(4 + (t5 & 1)) * NN + i] - p10, v, bits, stage, t5);
  }
  if (t2 >= 0) {
    float p0 = psp[0 * NN + i] * 0.8f + sumseg(partial, 0, i); psp[0 * NN + i] = p0;
    nb1[threadIdx.x] = lif_upd(1, i, p0, v, bits, stage, t2);
    float p1 = psp[1 * NN + i] * 0.8f + sumseg(partial, 1, i); psp[1 * NN + i] = p1;
    stash[(size_t)(t2 & 1) * NN + i] = 2.0f * p1;
    float p3 = psp[3 * NN + i] * 0.8f + sumseg(partial, 3, i); psp[3 * NN + i] = p3;
    nb4[threadIdx.x] = lif_upd(4, i, p3, v, bits, stage, t2);
    float p4 = psp[4 * NN + i] * 0.8f + sumseg(partial, 4, i); psp[4 * NN + i] = p4;
    stash[(size_t)(2 + (t2 & 1)) * NN + i] = 2.0f * p4;
  }
  if (t1 >= 0) {
    nb0[threadIdx.x] = lif_upd(0, i, IN0[(size_t)t1 * NN + i], v, bits, stage, t1);
    nb3[threadIdx.x] = lif_upd(3, i, IN3[(size_t)t1 * NN + i], v, bits, stage, t1);
  }
  __syncthreads();
  const int tid = threadIdx.x;
  if (t1 >= 0 && tid < 32) {
    int which = tid >> 3, w = tid & 7;
    const int kk[4] = {0, 1, 3, 4};
    mask_words(which < 2 ? nb0 : nb3, kk[which], delays, masks, blockIdx.x, w, t1 & 15);
  }
  if (t2 >= 0 && tid >= 32 && tid < 48) {
    int l = tid - 32, which = l >> 3, w = l & 7;
    mask_words(which ? nb4 : nb1, which ? 5 : 2, delays, masks, blockIdx.x, w, t2 & 15);
  }
  if (t3 >= 0 && tid >= 48 && tid < 80) {
    int l = tid - 48, which = l >> 3, w = l & 7;
    const int kk[4] = {6, 7, 8, 9};
    mask_words(which < 2 ? nb2 : nb5, kk[which], delays, masks, blockIdx.x, w, t3 & 15);
  }
  if (t4 >= 0 && tid >= 80 && tid < 88) {
    mask_words(nb6, 10, delays, masks, blockIdx.x, tid - 80, t4 & 15);
  }
}

// Final spike transpose: out[li][i][t] = stage[t][li][i]
__global__ void out_tr(const float* __restrict__ stage, float* __restrict__ out) {
  __shared__ float tile[32][33];
  const int li = blockIdx.z;
  const int i0 = blockIdx.x * 32, t0 = blockIdx.y * 32;
  int tx = threadIdx.x & 31, ty = threadIdx.x >> 5;
  #pragma unroll
  for (int m = 0; m < 4; ++m) {
    int tt = t0 + ty + m * 8;
    tile[ty + m * 8][tx] = (tt < NT) ? stage[((size_t)tt * 8 + li) * NN + i0 + tx] : 0.0f;
  }
  __syncthreads();
  #pragma unroll
  for (int m = 0; m < 4; ++m) {
    int ii = i0 + ty + m * 8;
    int tt = t0 + tx;
    if (tt < NT) out[((size_t)li * NN + ii) * NT + tt] = tile[tx][ty + m * 8];
  }
}

// ---------------- launch ----------------
extern "C" void kernel_launch(void* const* d_in, const int* in_sizes, int n_in,
                              void* d_out, int out_size, void* d_ws, size_t ws_size,
                              hipStream_t stream) {
  const float* stim   = (const float*)d_in[0];
  const float* Wsa    = (const float*)d_in[1];
  const float* Wra    = (const float*)d_in[2];
  const float* Wdel   = (const float*)d_in[3];
  const int*   delays = (const int*)d_in[4];
  float* out = (float*)d_out;
  float* ws  = (float*)d_ws;

  float* WT    = ws;
  float* IN0   = WT + (size_t)11 * NN * NN;
  float* IN3   = IN0 + (size_t)NN * NT;
  float* v     = IN3 + (size_t)NN * NT;
  float* psp   = v + 8 * NN;
  unsigned* bits  = (unsigned*)(psp + 11 * NN);
  unsigned* masks = bits + 8 * NN;
  float* part  = (float*)(masks + 11 * 128);
  float* stg   = part + (size_t)11 * SEG * NN;
  float* stash = stg + (size_t)NT * 8 * NN;
  float* wend  = stash + 6 * NN;
  if (ws_size < (size_t)(wend - ws) * sizeof(float)) return;

  // zero state: v(8N) + psp(11N) + bits(8N) contiguous
  hipMemsetAsync(v, 0, (size_t)(8 + 11 + 8) * NN * sizeof(float), stream);
  transpose_k<<<dim3(NN / 32, NN / 32, 11), 256, 0, stream>>>(Wdel, WT);
  dim3 gg(NN / 64, (NT + 63) / 64);
  gemm_in<0><<<gg, 256, 0, stream>>>(Wsa, stim, IN0);
  gemm_in<1><<<gg, 256, 0, stream>>>(Wra, stim, IN3);

  #define ECOMBO(a,b,c,d,e) e_combo<<<16, 256, 0, stream>>>(part, delays, v, psp, bits, \
      masks, stg, IN0, IN3, stash, a, b, c, d, e)
  #define GATH(nk, a,b,c,d,e,f) sp_gather6<<<dim3(4 * SEG, nk), 256, 0, stream>>>( \
      WT, masks, part, a, b, c, d, e, f)

  // prologue
  ECOMBO(0, -1, -1, -1, -1);            // E1@0
  GATH(4, 0, 1, 3, 4, 0, 0);            // G1@0  (nk=4 — round-3 bug was nk=1 here)
  ECOMBO(1, 0, -1, -1, -1);             // E1@1, E2@0

  // steady state: 8 launches per 2 steps
  for (int u = 0; u <= NT - 3; u += 2) {
    GATH(6, 2, 5, 0, 1, 3, 4);          // G2@u, G1@u+1
    ECOMBO(u + 2, u + 1, u, -1, -1);    // E1@u+2, E2@u+1, E3@u
    GATH(6, 6, 7, 8, 9, 2, 5);          // G3@u, G2@u+1
    ECOMBO(-1, -1, u + 1, u, -1);       // E3@u+1, E4@u
    GATH(5, 10, 6, 7, 8, 9, 0);         // G4@u, G3@u+1
    ECOMBO(-1, -1, -1, u + 1, u);       // E4@u+1, E5@u
    GATH(5, 0, 1, 3, 4, 10, 0);         // G1@u+2, G4@u+1
    ECOMBO(u + 3, u + 2, -1, -1, u + 1);// E1@u+3, E2@u+2, E5@u+1
  }

  // epilogue: finish t = NT-1 = 198 (E1,G1,E2 already done in last iteration)
  GATH(2, 2, 5, 0, 0, 0, 0);            // G2@198
  ECOMBO(-1, -1, NT - 1, -1, -1);       // E3@198
  GATH(4, 6, 7, 8, 9, 0, 0);            // G3@198
  ECOMBO(-1, -1, -1, NT - 1, -1);       // E4@198
  GATH(1, 10, 0, 0, 0, 0, 0);           // G4@198
  ECOMBO(-1, -1, -1, -1, NT - 1);       // E5@198

  out_tr<<<dim3(NN / 32, (NT + 31) / 32, 8), 256, 0, stream>>>(stg, out);
  #undef ECOMBO
  #undef GATH
}

// Round 5
// 5054.095 us; speedup vs baseline: 7.5273x; 2.9285x over previous
//
#include <hip/hip_runtime.h>

// ---------------- problem constants ----------------
#define NN   4096
#define TLEN 200
#define NT   199
#define NW   8       // spike-bit words per neuron (ceil(199/32)=7, +1 zero pad)

// GEMM tiling
#define BM 128
#define BT 64
#define BK 32

// ================= stimulus GEMM: out[t][i] = sum_j W[i][j] * X(j,t) =================
// MODE 0: X(j,t) = stim[j, t+1] - 3
// MODE 1: X(j,t) = (t+1>=4) ? |stim[j,t+1]-stim[j,t]|*10 : 0
template<int MODE>
__global__ __launch_bounds__(256) void gemm_stim(const float* __restrict__ W,
                                                 const float* __restrict__ stim,
                                                 float* __restrict__ out) {
  __shared__ float Ws[BK][BM + 4];
  __shared__ float Xs[BK][BT + 4];
  const int i0 = blockIdx.x * BM, t0 = blockIdx.y * BT;
  const int tid = threadIdx.x;
  const int tx = tid & 15, ty = tid >> 4;
  float acc[8][4] = {};
  for (int k0 = 0; k0 < NN; k0 += BK) {
    for (int q = tid; q < BM * BK; q += 256) {
      int r = q >> 5, kk = q & 31;
      Ws[kk][r] = W[(size_t)(i0 + r) * NN + k0 + kk];
    }
    {
      int kk = tid >> 3, ts = (tid & 7) * 8;
      int j = k0 + kk;
      #pragma unroll
      for (int b = 0; b < 8; ++b) {
        int tt = t0 + ts + b;
        float xv = 0.0f;
        if (tt < NT) {
          int tc = tt + 1;
          if (MODE == 0) {
            xv = stim[(size_t)j * TLEN + tc] - 3.0f;
          } else {
            xv = (tc >= 4)
               ? fabsf(stim[(size_t)j * TLEN + tc] - stim[(size_t)j * TLEN + tc - 1]) * 10.0f
               : 0.0f;
          }
        }
        Xs[kk][ts + b] = xv;
      }
    }
    __syncthreads();
    #pragma unroll
    for (int kk = 0; kk < BK; ++kk) {
      float4 x  = *(const float4*)&Xs[kk][tx * 4];
      float4 wa = *(const float4*)&Ws[kk][ty * 8];
      float4 wb = *(const float4*)&Ws[kk][ty * 8 + 4];
      float wv[8] = {wa.x, wa.y, wa.z, wa.w, wb.x, wb.y, wb.z, wb.w};
      float xv[4] = {x.x, x.y, x.z, x.w};
      #pragma unroll
      for (int a = 0; a < 8; ++a)
        #pragma unroll
        for (int b = 0; b < 4; ++b) acc[a][b] += wv[a] * xv[b];
    }
    __syncthreads();
  }
  #pragma unroll
  for (int b = 0; b < 4; ++b) {
    int t = t0 + tx * 4 + b;
    if (t < NT) {
      float4 o0 = {acc[0][b], acc[1][b], acc[2][b], acc[3][b]};
      float4 o1 = {acc[4][b], acc[5][b], acc[6][b], acc[7][b]};
      *(float4*)&out[(size_t)t * NN + i0 + ty * 8]     = o0;
      *(float4*)&out[(size_t)t * NN + i0 + ty * 8 + 4] = o1;
    }
  }
}

// ================= synapse GEMM over ALL time steps =================
// u[k][t][i] = sum_j Wdel[k][i][j] * bit(Sb[pre][j], t - delays[k][j])
// kpack/prepack: 4-bit fields per blockIdx.z.
__global__ __launch_bounds__(256) void gemm_syn(const float* __restrict__ Wdel,
                                                const int* __restrict__ delays,
                                                const unsigned* __restrict__ Sb,
                                                float* __restrict__ u,
                                                int kpack, int prepack) {
  const int bz = blockIdx.z;
  const int k   = (kpack   >> (4 * bz)) & 15;
  const int pre = (prepack >> (4 * bz)) & 15;
  const float* Wk = Wdel + (size_t)k * NN * NN;
  const unsigned* S = Sb + (size_t)pre * NW * NN;
  const int* dl = delays + (size_t)k * NN;
  float* uk = u + (size_t)k * NT * NN;

  __shared__ float Ws[BK][BM + 4];
  __shared__ float Xs[BK][BT + 4];
  const int i0 = blockIdx.x * BM, t0 = blockIdx.y * BT;
  const int tid = threadIdx.x;
  const int tx = tid & 15, ty = tid >> 4;
  float acc[8][4] = {};
  for (int k0 = 0; k0 < NN; k0 += BK) {
    for (int q = tid; q < BM * BK; q += 256) {
      int r = q >> 5, kk = q & 31;
      Ws[kk][r] = Wk[(size_t)(i0 + r) * NN + k0 + kk];
    }
    {
      int kk = tid >> 3, ts = (tid & 7) * 8;
      int j = k0 + kk;
      int d = dl[j];
      int tsrc = t0 + ts - d;                 // source bit index of first element
      int w0 = tsrc >> 5;                     // floor shift (tsrc may be negative)
      int sh = tsrc & 31;
      unsigned lo = (w0 >= 0 && w0 < NW) ? S[(size_t)w0 * NN + j] : 0u;
      int w1 = w0 + 1;
      unsigned hi = (w1 >= 0 && w1 < NW) ? S[(size_t)w1 * NN + j] : 0u;
      unsigned wnd = sh ? ((lo >> sh) | (hi << (32 - sh))) : lo;
      #pragma unroll
      for (int b = 0; b < 8; ++b) Xs[kk][ts + b] = (float)((wnd >> b) & 1u);
    }
    __syncthreads();
    #pragma unroll
    for (int kk = 0; kk < BK; ++kk) {
      float4 x  = *(const float4*)&Xs[kk][tx * 4];
      float4 wa = *(const float4*)&Ws[kk][ty * 8];
      float4 wb = *(const float4*)&Ws[kk][ty * 8 + 4];
      float wv[8] = {wa.x, wa.y, wa.z, wa.w, wb.x, wb.y, wb.z, wb.w};
      float xv[4] = {x.x, x.y, x.z, x.w};
      #pragma unroll
      for (int a = 0; a < 8; ++a)
        #pragma unroll
        for (int b = 0; b < 4; ++b) acc[a][b] += wv[a] * xv[b];
    }
    __syncthreads();
  }
  #pragma unroll
  for (int b = 0; b < 4; ++b) {
    int t = t0 + tx * 4 + b;
    if (t < NT) {
      float4 o0 = {acc[0][b], acc[1][b], acc[2][b], acc[3][b]};
      float4 o1 = {acc[4][b], acc[5][b], acc[6][b], acc[7][b]};
      *(float4*)&uk[(size_t)t * NN + i0 + ty * 8]     = o0;
      *(float4*)&uk[(size_t)t * NN + i0 + ty * 8 + 4] = o1;
    }
  }
}

// ================= LIF / PSP register scans =================
__device__ __forceinline__ void flush_bits(unsigned* sb, int j, int t, unsigned& bits) {
  if ((t & 31) == 31 || t == NT - 1) { sb[(size_t)(t >> 5) * NN + j] = bits; bits = 0; }
}

// round a: L0 from IN0, L3 from IN3
__global__ void scan_a(const float* __restrict__ IN0, const float* __restrict__ IN3,
                       unsigned* __restrict__ Sb) {
  const int j = blockIdx.x * 256 + threadIdx.x;
  const float* in = blockIdx.y ? IN3 : IN0;
  unsigned* sb = Sb + (size_t)(blockIdx.y ? 3 : 0) * NW * NN;
  float v = 0.f; unsigned bits = 0;
  for (int t = 0; t < NT; ++t) {
    float vn = v * 0.9f + in[(size_t)t * NN + j];
    unsigned s = vn >= 1.0f;
    v = s ? 0.f : vn;
    bits |= s << (t & 31);
    flush_bits(sb, j, t, bits);
  }
}

// round b: y=0: L1 (psp0 -> lif1, psp1 -> p1s=2*psp1); y=1: L4 (psp3 -> lif4, psp4 -> p4s)
__global__ void scan_b(const float* __restrict__ u, unsigned* __restrict__ Sb,
                       float* __restrict__ p1s, float* __restrict__ p4s) {
  const int j = blockIdx.x * 256 + threadIdx.x;
  const int sa = blockIdx.y;
  const float* ua = u + (size_t)(sa ? 3 : 0) * NT * NN;
  const float* ub = u + (size_t)(sa ? 4 : 1) * NT * NN;
  float* ps = sa ? p4s : p1s;
  unsigned* sb = Sb + (size_t)(sa ? 4 : 1) * NW * NN;
  float v = 0.f, pa = 0.f, pb = 0.f; unsigned bits = 0;
  for (int t = 0; t < NT; ++t) {
    pa = pa * 0.8f + ua[(size_t)t * NN + j];
    float vn = v * 0.9f + pa;
    unsigned s = vn >= 1.0f;
    v = s ? 0.f : vn;
    bits |= s << (t & 31);
    flush_bits(sb, j, t, bits);
    pb = pb * 0.8f + ub[(size_t)t * NN + j];
    ps[(size_t)t * NN + j] = 2.0f * pb;
  }
}

// round c: y=0: L2 (psp2; inp = p1s - psp2); y=1: L5 (psp5; inp = p4s - psp5)
__global__ void scan_c(const float* __restrict__ u, unsigned* __restrict__ Sb,
                       const float* __restrict__ p1s, const float* __restrict__ p4s) {
  const int j = blockIdx.x * 256 + threadIdx.x;
  const int sa = blockIdx.y;
  const float* ua = u + (size_t)(sa ? 5 : 2) * NT * NN;
  const float* ps = sa ? p4s : p1s;
  unsigned* sb = Sb + (size_t)(sa ? 5 : 2) * NW * NN;
  float v = 0.f, p = 0.f; unsigned bits = 0;
  for (int t = 0; t < NT; ++t) {
    p = p * 0.8f + ua[(size_t)t * NN + j];
    float vn = v * 0.9f + (ps[(size_t)t * NN + j] - p);
    unsigned s = vn >= 1.0f;
    v = s ? 0.f : vn;
    bits |= s << (t & 31);
    flush_bits(sb, j, t, bits);
  }
}

// round d: y=0: L6 (psp6+psp8 -> lif6); y=1: psp7,psp9 -> p79s = 2*psp7+2*psp9
__global__ void scan_d(const float* __restrict__ u, unsigned* __restrict__ Sb,
                       float* __restrict__ p79s) {
  const int j = blockIdx.x * 256 + threadIdx.x;
  if (blockIdx.y == 0) {
    const float* u6 = u + (size_t)6 * NT * NN;
    const float* u8 = u + (size_t)8 * NT * NN;
    unsigned* sb = Sb + (size_t)6 * NW * NN;
    float v = 0.f, p6 = 0.f, p8 = 0.f; unsigned bits = 0;
    for (int t = 0; t < NT; ++t) {
      p6 = p6 * 0.8f + u6[(size_t)t * NN + j];
      p8 = p8 * 0.8f + u8[(size_t)t * NN + j];
      float vn = v * 0.9f + (p6 + p8);
      unsigned s = vn >= 1.0f;
      v = s ? 0.f : vn;
      bits |= s << (t & 31);
      flush_bits(sb, j, t, bits);
    }
  } else {
    const float* u7 = u + (size_t)7 * NT * NN;
    const float* u9 = u + (size_t)9 * NT * NN;
    float p7 = 0.f, p9 = 0.f;
    for (int t = 0; t < NT; ++t) {
      p7 = p7 * 0.8f + u7[(size_t)t * NN + j];
      p9 = p9 * 0.8f + u9[(size_t)t * NN + j];
      p79s[(size_t)t * NN + j] = 2.0f * p7 + 2.0f * p9;
    }
  }
}

// round e: L7 (psp10; inp = p79s - psp10)
__global__ void scan_e(const float* __restrict__ u, unsigned* __restrict__ Sb,
                       const float* __restrict__ p79s) {
  const int j = blockIdx.x * 256 + threadIdx.x;
  const float* ua = u + (size_t)10 * NT * NN;
  unsigned* sb = Sb + (size_t)7 * NW * NN;
  float v = 0.f, p = 0.f; unsigned bits = 0;
  for (int t = 0; t < NT; ++t) {
    p = p * 0.8f + ua[(size_t)t * NN + j];
    float vn = v * 0.9f + (p79s[(size_t)t * NN + j] - p);
    unsigned s = vn >= 1.0f;
    v = s ? 0.f : vn;
    bits |= s << (t & 31);
    flush_bits(sb, j, t, bits);
  }
}

// ================= bit -> float expansion into output =================
// out[li][j][t] = bit t of Sb[li][.][j]
__global__ void expand_k(const unsigned* __restrict__ Sb, float* __restrict__ out) {
  const int j = blockIdx.x * 256 + threadIdx.x;
  const int w = blockIdx.y, li = blockIdx.z;
  unsigned bits = Sb[((size_t)li * NW + w) * NN + j];
  float* o = out + ((size_t)li * NN + j) * NT + w * 32;
  int nb = NT - w * 32; if (nb > 32) nb = 32;
  for (int b = 0; b < nb; ++b) o[b] = (float)((bits >> b) & 1u);
}

// ================= launch =================
extern "C" void kernel_launch(void* const* d_in, const int* in_sizes, int n_in,
                              void* d_out, int out_size, void* d_ws, size_t ws_size,
                              hipStream_t stream) {
  const float* stim   = (const float*)d_in[0];
  const float* Wsa    = (const float*)d_in[1];
  const float* Wra    = (const float*)d_in[2];
  const float* Wdel   = (const float*)d_in[3];
  const int*   delays = (const int*)d_in[4];
  float* out = (float*)d_out;
  float* ws  = (float*)d_ws;

  const size_t TN = (size_t)NT * NN;
  float* IN0  = ws;
  float* IN3  = IN0 + TN;
  float* u    = IN3 + TN;            // 11 * TN
  float* p1s  = u + 11 * TN;
  float* p4s  = p1s + TN;
  float* p79s = p4s + TN;
  unsigned* Sb = (unsigned*)(p79s + TN);   // 8 * NW * NN words
  size_t need = ((size_t)(16 * TN) + (size_t)8 * NW * NN) * 4;
  if (ws_size < need) return;

  hipMemsetAsync(Sb, 0, (size_t)8 * NW * NN * sizeof(unsigned), stream);

  dim3 gsz(NN / BM, (NT + BT - 1) / BT);        // 32 x 4
  gemm_stim<0><<<gsz, 256, 0, stream>>>(Wsa, stim, IN0);
  gemm_stim<1><<<gsz, 256, 0, stream>>>(Wra, stim, IN3);
  scan_a<<<dim3(16, 2), 256, 0, stream>>>(IN0, IN3, Sb);

  // round A: syn {0,1,3,4}, pre {0,0,3,3}
  gemm_syn<<<dim3(NN / BM, 4, 4), 256, 0, stream>>>(Wdel, delays, Sb, u, 0x4310, 0x3300);
  scan_b<<<dim3(16, 2), 256, 0, stream>>>(u, Sb, p1s, p4s);

  // round B: syn {2,5}, pre {1,4}
  gemm_syn<<<dim3(NN / BM, 4, 2), 256, 0, stream>>>(Wdel, delays, Sb, u, 0x52, 0x41);
  scan_c<<<dim3(16, 2), 256, 0, stream>>>(u, Sb, p1s, p4s);

  // round C: syn {6,7,8,9}, pre {2,2,5,5}
  gemm_syn<<<dim3(NN / BM, 4, 4), 256, 0, stream>>>(Wdel, delays, Sb, u, 0x9876, 0x5522);
  scan_d<<<dim3(16, 2), 256, 0, stream>>>(u, Sb, p79s);

  // round D: syn {10}, pre {6}
  gemm_syn<<<dim3(NN / BM, 4, 1), 256, 0, stream>>>(Wdel, delays, Sb, u, 10, 6);
  scan_e<<<dim3(16, 1), 256, 0, stream>>>(u, Sb, p79s);

  expand_k<<<dim3(16, 7, 8), 256, 0, stream>>>(Sb, out);
}